// Round 3
// baseline (316.618 us; speedup 1.0000x reference)
//
#include <hip/hip_runtime.h>
#include <hip/hip_bf16.h>

#define DIM   1024
#define BATCH 8192
#define KV    16
#define MB    32            // batches per fused block
#define ROWEL 1280          // padded u row length (elements); pos = d + ((d>>5)<<3) < 1280

typedef __attribute__((ext_vector_type(4))) float f32x4;
typedef __attribute__((ext_vector_type(8))) short short8;

static __device__ __forceinline__ unsigned short f2bf(float x) {
  return __builtin_bit_cast(unsigned short, __float2bfloat16(x));
}
static __device__ __forceinline__ float bf2f(unsigned short x) {
  return __bfloat162float(__builtin_bit_cast(__hip_bfloat16, x));
}

static __device__ __forceinline__ void gl_lds16(const unsigned short* g, unsigned short* l) {
  __builtin_amdgcn_global_load_lds(
      (const __attribute__((address_space(1))) void*)g,
      (__attribute__((address_space(3))) void*)l, 16, 0, 0);
}

// ---------------- kernel 1: query f32 -> bf16 ----------------
__global__ __launch_bounds__(256) void convert_q(const f32x4* __restrict__ in,
                                                 ushort4* __restrict__ out, int n4) {
  int i = blockIdx.x * blockDim.x + threadIdx.x;
  int stride = gridDim.x * blockDim.x;
  for (; i < n4; i += stride) {
    f32x4 f = in[i];
    ushort4 o;
    o.x = f2bf(f.x); o.y = f2bf(f.y); o.z = f2bf(f.z); o.w = f2bf(f.w);
    out[i] = o;
  }
}

// ---------------- kernel 2: Wq,Wk f32 -> transposed bf16 ----------------
__global__ __launch_bounds__(256) void transpose_w(const float* __restrict__ Wq,
                                                   const float* __restrict__ Wk,
                                                   unsigned short* __restrict__ WqT,
                                                   unsigned short* __restrict__ WkT) {
  __shared__ float tile[32][33];
  const float* src = blockIdx.z ? Wk : Wq;
  unsigned short* dst = blockIdx.z ? WkT : WqT;
  int x = blockIdx.x * 32 + threadIdx.x;
  int y0 = blockIdx.y * 32;
  #pragma unroll
  for (int i = threadIdx.y; i < 32; i += 8)
    tile[i][threadIdx.x] = src[(size_t)(y0 + i) * DIM + x];
  __syncthreads();
  int x2 = blockIdx.y * 32 + threadIdx.x;
  int y2 = blockIdx.x * 32;
  #pragma unroll
  for (int i = threadIdx.y; i < 32; i += 8)
    dst[(size_t)(y2 + i) * DIM + x2] = f2bf(tile[threadIdx.x][i]);
}

// ---------------- kernel 3: Mt = WkT x WqT^T, 64x64 tiles (256 blocks) ----------------
__global__ __launch_bounds__(256) void gemm_nt64(const unsigned short* __restrict__ A,
                                                 const unsigned short* __restrict__ B,
                                                 unsigned short* __restrict__ C,
                                                 int N, int K) {
  __shared__ __align__(16) unsigned short As[64 * 32];
  __shared__ __align__(16) unsigned short Bs[64 * 32];
  const int tid = threadIdx.x;
  const int lane = tid & 63;
  const int wave = tid >> 6;
  const int wr = wave >> 1, wc = wave & 1;
  const size_t bm = (size_t)blockIdx.x * 64;
  const size_t bn = (size_t)blockIdx.y * 64;

  f32x4 acc[2][2];
  #pragma unroll
  for (int m = 0; m < 2; ++m)
    #pragma unroll
    for (int n = 0; n < 2; ++n)
      acc[m][n] = (f32x4){0.f, 0.f, 0.f, 0.f};

  const int r0 = tid >> 2;
  const int cc = (tid & 3) * 8;
  const int kg = lane >> 4;
  const int rowf = lane & 15;

  for (int kt = 0; kt < K; kt += 32) {
    gl_lds16(A + (bm + r0) * K + kt + cc, As + tid * 8);
    gl_lds16(B + (bn + r0) * K + kt + cc, Bs + tid * 8);
    __syncthreads();
    short8 af[2], bfr[2];
    #pragma unroll
    for (int m = 0; m < 2; ++m)
      af[m] = *(const short8*)(As + ((wr * 32 + m * 16 + rowf) * 32 + kg * 8));
    #pragma unroll
    for (int n = 0; n < 2; ++n)
      bfr[n] = *(const short8*)(Bs + ((wc * 32 + n * 16 + rowf) * 32 + kg * 8));
    #pragma unroll
    for (int m = 0; m < 2; ++m)
      #pragma unroll
      for (int n = 0; n < 2; ++n)
        acc[m][n] = __builtin_amdgcn_mfma_f32_16x16x32_bf16(af[m], bfr[n], acc[m][n], 0, 0, 0);
    __syncthreads();
  }

  const int rq = (lane >> 4) * 4;
  const int colf = lane & 15;
  #pragma unroll
  for (int m = 0; m < 2; ++m)
    #pragma unroll
    for (int n = 0; n < 2; ++n)
      #pragma unroll
      for (int i = 0; i < 4; ++i)
        C[(bm + wr * 32 + m * 16 + rq + i) * N + bn + wc * 32 + n * 16 + colf] =
            f2bf(acc[m][n][i]);
}

// ---------------- kernel 4: fused u-GEMM + attention epilogue ----------------
// Per block: 32 batches. Phase 1: u[32][1024] = qbf_panel x Mt^T via MFMA
// (A from LDS, B-frags straight from L2), u -> LDS (bf16, padded layout).
// Phase 2: per wave, 4 batches sequentially; coalesced 64-lane K/V row reads,
// in-wave shfl reductions, softmax, gate, normalize, store.
__global__ __launch_bounds__(512, 2) void fused_attn(
    const unsigned short* __restrict__ qbf,   // [8192][1024] bf16
    const unsigned short* __restrict__ Mt,    // [1024][1024] bf16, Mt[n][k]
    const float* __restrict__ key,
    const float* __restrict__ value,
    const float* __restrict__ Wa,
    const float* __restrict__ ba,
    float* __restrict__ out) {
  // Aliased LDS: phase 1 uses S[0..32767] as A-tiles [kt][32][32];
  // after a barrier the same buffer holds u[32][ROWEL] (bf16, padded).
  __shared__ __align__(16) unsigned short S[MB * ROWEL];   // 80 KB
  const int tid = threadIdx.x;
  const int lane = tid & 63;
  const int wave = tid >> 6;            // 0..7
  const size_t b0 = (size_t)blockIdx.x * MB;

  // ---- stage A (qbf panel, 32x1024 bf16 = 64KB) into LDS as [kt][32][32] ----
  #pragma unroll
  for (int it = 0; it < 8; ++it) {
    int et = (it * 512 + tid) * 8;      // element index, linear in LDS
    int kt = et >> 10;                  // 1024 elements per k-tile
    int idx = et & 1023;
    int r = idx >> 5;
    int c = idx & 31;
    gl_lds16(qbf + (b0 + r) * DIM + kt * 32 + c, S + et);
  }
  __syncthreads();

  // ---- phase 1: u = A x Mt^T; wave w owns u cols [w*128, w*128+128) ----
  {
    const int rowf = lane & 15;
    const int kg = lane >> 4;
    f32x4 acc[2][8];
    #pragma unroll
    for (int mf = 0; mf < 2; ++mf)
      #pragma unroll
      for (int f = 0; f < 8; ++f)
        acc[mf][f] = (f32x4){0.f, 0.f, 0.f, 0.f};

    const unsigned short* Bbase = Mt + (size_t)(wave * 128 + rowf) * DIM + kg * 8;
    for (int kt = 0; kt < 32; ++kt) {
      short8 a0 = *(const short8*)(S + kt * 1024 + rowf * 32 + kg * 8);
      short8 a1 = *(const short8*)(S + kt * 1024 + (16 + rowf) * 32 + kg * 8);
      #pragma unroll
      for (int f = 0; f < 8; ++f) {
        short8 bf8 = *(const short8*)(Bbase + (size_t)f * 16 * DIM + kt * 32);
        acc[0][f] = __builtin_amdgcn_mfma_f32_16x16x32_bf16(a0, bf8, acc[0][f], 0, 0, 0);
        acc[1][f] = __builtin_amdgcn_mfma_f32_16x16x32_bf16(a1, bf8, acc[1][f], 0, 0, 0);
      }
    }
    __syncthreads();   // all A reads done -> safe to overwrite with u

    // write u (bf16) into padded layout: row = batch, pos(c) = c + ((c>>5)<<3)
    #pragma unroll
    for (int mf = 0; mf < 2; ++mf)
      #pragma unroll
      for (int f = 0; f < 8; ++f) {
        int c = wave * 128 + f * 16 + rowf;
        int pos = c + ((c >> 5) << 3);
        #pragma unroll
        for (int i = 0; i < 4; ++i)
          S[(mf * 16 + kg * 4 + i) * ROWEL + pos] = f2bf(acc[mf][f][i]);
      }
  }
  __syncthreads();

  // ---- phase 2: per wave, batches (wave*4 .. wave*4+4) sequentially ----
  // lane owns dims d = lane*4 + r*256, r = 0..3 (fully coalesced rows)
  float wav[16];
  #pragma unroll
  for (int r = 0; r < 4; ++r) {
    f32x4 w4 = *(const f32x4*)(Wa + r * 256 + lane * 4);
    wav[r * 4 + 0] = w4.x; wav[r * 4 + 1] = w4.y;
    wav[r * 4 + 2] = w4.z; wav[r * 4 + 3] = w4.w;
  }
  const float ba0 = ba[0];

  for (int g = 0; g < 4; ++g) {
    const int bl = wave * 4 + g;
    const size_t b = b0 + bl;

    float qf[16], uu[16];
    #pragma unroll
    for (int r = 0; r < 4; ++r) {
      int d = lane * 4 + r * 256;
      ushort4 q4v = *(const ushort4*)(qbf + b * DIM + d);
      int pos = d + ((d >> 5) << 3);
      ushort4 u4v = *(const ushort4*)(S + bl * ROWEL + pos);
      qf[r * 4 + 0] = bf2f(q4v.x); qf[r * 4 + 1] = bf2f(q4v.y);
      qf[r * 4 + 2] = bf2f(q4v.z); qf[r * 4 + 3] = bf2f(q4v.w);
      uu[r * 4 + 0] = bf2f(u4v.x); uu[r * 4 + 1] = bf2f(u4v.y);
      uu[r * 4 + 2] = bf2f(u4v.z); uu[r * 4 + 3] = bf2f(u4v.w);
    }

    float s[17];
    float t0 = 0.f, ad = 0.f;
    #pragma unroll
    for (int i = 0; i < 16; ++i) { t0 += qf[i] * uu[i]; ad += qf[i] * wav[i]; }
    s[0] = t0;

    const float* krow = key + b * (KV * DIM);
    #pragma unroll
    for (int j = 1; j <= 16; ++j) {
      float a2 = 0.f;
      #pragma unroll
      for (int r = 0; r < 4; ++r) {
        f32x4 kv = __builtin_nontemporal_load(
            (const f32x4*)(krow + (size_t)(j - 1) * DIM + r * 256) + lane);
        a2 += kv.x * uu[r * 4] + kv.y * uu[r * 4 + 1] +
              kv.z * uu[r * 4 + 2] + kv.w * uu[r * 4 + 3];
      }
      s[j] = a2;
    }

    #pragma unroll
    for (int m = 32; m >= 1; m >>= 1) {
      #pragma unroll
      for (int j = 0; j < 17; ++j) s[j] += __shfl_xor(s[j], m);
      ad += __shfl_xor(ad, m);
    }

    float mx = -1e30f;
    #pragma unroll
    for (int j = 0; j < 17; ++j) { s[j] *= 0.03125f; mx = fmaxf(mx, s[j]); }
    float den = 0.f;
    #pragma unroll
    for (int j = 0; j < 17; ++j) { s[j] = expf(s[j] - mx); den += s[j]; }
    float alpha = 1.f / (1.f + expf(-(ad + ba0)));
    float am = alpha / den;

    float off[16];
    float w0p = 1.f + am * s[0];
    #pragma unroll
    for (int i = 0; i < 16; ++i) off[i] = qf[i] * w0p;

    const float* vrow = value + b * (KV * DIM);
    #pragma unroll
    for (int j = 1; j <= 16; ++j) {
      float wj = am * s[j];
      #pragma unroll
      for (int r = 0; r < 4; ++r) {
        f32x4 vv = __builtin_nontemporal_load(
            (const f32x4*)(vrow + (size_t)(j - 1) * DIM + r * 256) + lane);
        off[r * 4 + 0] += wj * vv.x; off[r * 4 + 1] += wj * vv.y;
        off[r * 4 + 2] += wj * vv.z; off[r * 4 + 3] += wj * vv.w;
      }
    }

    float nq = 0.f;
    #pragma unroll
    for (int i = 0; i < 16; ++i) nq += off[i] * off[i];
    #pragma unroll
    for (int m = 32; m >= 1; m >>= 1) nq += __shfl_xor(nq, m);
    float inv = 1.f / fmaxf(sqrtf(nq), 1e-12f);

    #pragma unroll
    for (int r = 0; r < 4; ++r) {
      f32x4 o;
      o.x = off[r * 4 + 0] * inv; o.y = off[r * 4 + 1] * inv;
      o.z = off[r * 4 + 2] * inv; o.w = off[r * 4 + 3] * inv;
      *((f32x4*)(out + b * DIM + r * 256) + lane) = o;
    }
  }
}

// ---------------- launcher ----------------
extern "C" void kernel_launch(void* const* d_in, const int* in_sizes, int n_in,
                              void* d_out, int out_size, void* d_ws, size_t ws_size,
                              hipStream_t stream) {
  const float* query = (const float*)d_in[0];
  const float* key   = (const float*)d_in[1];
  const float* value = (const float*)d_in[2];
  const float* Wq    = (const float*)d_in[3];
  const float* Wk    = (const float*)d_in[4];
  const float* Wa    = (const float*)d_in[5];
  const float* ba    = (const float*)d_in[6];

  unsigned short* qbf = (unsigned short*)d_ws;              // 16 MiB
  unsigned short* WqT = qbf + (size_t)BATCH * DIM;          //  2 MiB
  unsigned short* WkT = WqT + (size_t)DIM * DIM;            //  2 MiB
  unsigned short* Mt  = WkT + (size_t)DIM * DIM;            //  2 MiB

  convert_q<<<2048, 256, 0, stream>>>((const f32x4*)query, (ushort4*)qbf, BATCH * DIM / 4);
  transpose_w<<<dim3(32, 32, 2), dim3(32, 8), 0, stream>>>(Wq, Wk, WqT, WkT);
  // Mt = WkT x WqT^T  (1024^3, bf16 out), 64^2 tiles -> 256 blocks
  gemm_nt64<<<dim3(16, 16), 256, 0, stream>>>(WkT, WqT, Mt, DIM, DIM);
  // fused u-GEMM + scores/softmax/attn/gate/normalize
  fused_attn<<<BATCH / MB, 512, 0, stream>>>(qbf, Mt, key, value, Wa, ba, (float*)d_out);
}

// Round 4
// 313.266 us; speedup vs baseline: 1.0107x; 1.0107x over previous
//
#include <hip/hip_runtime.h>
#include <hip/hip_bf16.h>

#define DIM   1024
#define BATCH 8192
#define KV    16
#define SCP   20          // padded score row (17 used)

typedef __attribute__((ext_vector_type(4))) float f32x4;
typedef __attribute__((ext_vector_type(8))) short short8;

static __device__ __forceinline__ unsigned short f2bf(float x) {
  return __builtin_bit_cast(unsigned short, __float2bfloat16(x));
}
static __device__ __forceinline__ float bf2f(unsigned short x) {
  return __bfloat162float(__builtin_bit_cast(__hip_bfloat16, x));
}
static __device__ __forceinline__ float dot4(f32x4 a, f32x4 b) {
  return a.x * b.x + a.y * b.y + a.z * b.z + a.w * b.w;
}

static __device__ __forceinline__ void gl_lds16(const unsigned short* g, unsigned short* l) {
  __builtin_amdgcn_global_load_lds(
      (const __attribute__((address_space(1))) void*)g,
      (__attribute__((address_space(3))) void*)l, 16, 0, 0);
}

// ---------------- kernel 1: query f32 -> bf16, plus zero the scores buffer ----------------
__global__ __launch_bounds__(256) void convert_q(const f32x4* __restrict__ in,
                                                 ushort4* __restrict__ out, int n4,
                                                 f32x4* __restrict__ zbuf, int nz4) {
  int i = blockIdx.x * blockDim.x + threadIdx.x;
  int stride = gridDim.x * blockDim.x;
  for (int k = i; k < n4; k += stride) {
    f32x4 f = in[k];
    ushort4 o;
    o.x = f2bf(f.x); o.y = f2bf(f.y); o.z = f2bf(f.z); o.w = f2bf(f.w);
    out[k] = o;
  }
  for (int k = i; k < nz4; k += stride) zbuf[k] = (f32x4){0.f, 0.f, 0.f, 0.f};
}

// ---------------- kernel 2: Wq,Wk f32 -> transposed bf16 ----------------
__global__ __launch_bounds__(256) void transpose_w(const float* __restrict__ Wq,
                                                   const float* __restrict__ Wk,
                                                   unsigned short* __restrict__ WqT,
                                                   unsigned short* __restrict__ WkT) {
  __shared__ float tile[32][33];
  const float* src = blockIdx.z ? Wk : Wq;
  unsigned short* dst = blockIdx.z ? WkT : WqT;
  int x = blockIdx.x * 32 + threadIdx.x;
  int y0 = blockIdx.y * 32;
  #pragma unroll
  for (int i = threadIdx.y; i < 32; i += 8)
    tile[i][threadIdx.x] = src[(size_t)(y0 + i) * DIM + x];
  __syncthreads();
  int x2 = blockIdx.y * 32 + threadIdx.x;
  int y2 = blockIdx.x * 32;
  #pragma unroll
  for (int i = threadIdx.y; i < 32; i += 8)
    dst[(size_t)(y2 + i) * DIM + x2] = f2bf(tile[threadIdx.x][i]);
}

// ---------------- kernel 3: Mt = WkT x WqT^T, 64x64 tiles (256 blocks) ----------------
__global__ __launch_bounds__(256) void gemm_nt64(const unsigned short* __restrict__ A,
                                                 const unsigned short* __restrict__ B,
                                                 unsigned short* __restrict__ C,
                                                 int N, int K) {
  __shared__ __align__(16) unsigned short As[64 * 32];
  __shared__ __align__(16) unsigned short Bs[64 * 32];
  const int tid = threadIdx.x;
  const int lane = tid & 63;
  const int wave = tid >> 6;
  const int wr = wave >> 1, wc = wave & 1;
  const size_t bm = (size_t)blockIdx.x * 64;
  const size_t bn = (size_t)blockIdx.y * 64;

  f32x4 acc[2][2];
  #pragma unroll
  for (int m = 0; m < 2; ++m)
    #pragma unroll
    for (int n = 0; n < 2; ++n)
      acc[m][n] = (f32x4){0.f, 0.f, 0.f, 0.f};

  const int r0 = tid >> 2;
  const int cc = (tid & 3) * 8;
  const int kg = lane >> 4;
  const int rowf = lane & 15;

  for (int kt = 0; kt < K; kt += 32) {
    gl_lds16(A + (bm + r0) * K + kt + cc, As + tid * 8);
    gl_lds16(B + (bn + r0) * K + kt + cc, Bs + tid * 8);
    __syncthreads();
    short8 af[2], bfr[2];
    #pragma unroll
    for (int m = 0; m < 2; ++m)
      af[m] = *(const short8*)(As + ((wr * 32 + m * 16 + rowf) * 32 + kg * 8));
    #pragma unroll
    for (int n = 0; n < 2; ++n)
      bfr[n] = *(const short8*)(Bs + ((wc * 32 + n * 16 + rowf) * 32 + kg * 8));
    #pragma unroll
    for (int m = 0; m < 2; ++m)
      #pragma unroll
      for (int n = 0; n < 2; ++n)
        acc[m][n] = __builtin_amdgcn_mfma_f32_16x16x32_bf16(af[m], bfr[n], acc[m][n], 0, 0, 0);
    __syncthreads();
  }

  const int rq = (lane >> 4) * 4;
  const int colf = lane & 15;
  #pragma unroll
  for (int m = 0; m < 2; ++m)
    #pragma unroll
    for (int n = 0; n < 2; ++n)
      #pragma unroll
      for (int i = 0; i < 4; ++i)
        C[(bm + wr * 32 + m * 16 + rq + i) * N + bn + wc * 32 + n * 16 + colf] =
            f2bf(acc[m][n][i]);
}

// ---------------- kernel 4: u-GEMM (tile stays in LDS) + partial scores ----------------
// Tile 128 batches x 128 dims. After the K-loop, u-tile -> LDS (bf16, row stride 136).
// Then stream this block's K-slices key[b, j, bn:bn+128] (read exactly once globally)
// and q-slice qbf[b, bn:bn+128]; atomicAdd partial dots into scores[b][j] (j=0..16).
// u never touches HBM.
__global__ __launch_bounds__(256) void gemm_u_scores(
    const unsigned short* __restrict__ qbf,
    const unsigned short* __restrict__ Mt,
    const float* __restrict__ key,
    float* __restrict__ scores) {
  __shared__ __align__(16) unsigned short S[128 * 136];   // 34816 B (union: staging | u-tile)
  unsigned short* As = S;            // 8 KB
  unsigned short* Bs = S + 4096;     // 8 KB

  const int cpx = gridDim.x >> 3;    // XCD swizzle (512 % 8 == 0)
  const int wg = (blockIdx.x & 7) * cpx + (blockIdx.x >> 3);
  const size_t bm = (size_t)(wg >> 3) * 128;   // batch tile
  const size_t bn = (size_t)(wg & 7) * 128;    // dim tile

  const int tid = threadIdx.x;
  const int lane = tid & 63;
  const int wave = tid >> 6;
  const int wr = wave >> 1, wc = wave & 1;

  f32x4 acc[4][4];
  #pragma unroll
  for (int m = 0; m < 4; ++m)
    #pragma unroll
    for (int n = 0; n < 4; ++n)
      acc[m][n] = (f32x4){0.f, 0.f, 0.f, 0.f};

  const int r0 = tid >> 2;
  const int r1 = 64 + (tid >> 2);
  const int cc = (tid & 3) * 8;
  const int kg = lane >> 4;
  const int rowf = lane & 15;

  for (int kt = 0; kt < DIM; kt += 32) {
    gl_lds16(qbf + (bm + r0) * DIM + kt + cc, As + tid * 8);
    gl_lds16(qbf + (bm + r1) * DIM + kt + cc, As + 2048 + tid * 8);
    gl_lds16(Mt + (bn + r0) * DIM + kt + cc, Bs + tid * 8);
    gl_lds16(Mt + (bn + r1) * DIM + kt + cc, Bs + 2048 + tid * 8);
    __syncthreads();
    short8 af[4], bfr[4];
    #pragma unroll
    for (int m = 0; m < 4; ++m)
      af[m] = *(const short8*)(As + ((wr * 64 + m * 16 + rowf) * 32 + kg * 8));
    #pragma unroll
    for (int n = 0; n < 4; ++n)
      bfr[n] = *(const short8*)(Bs + ((wc * 64 + n * 16 + rowf) * 32 + kg * 8));
    #pragma unroll
    for (int m = 0; m < 4; ++m)
      #pragma unroll
      for (int n = 0; n < 4; ++n)
        acc[m][n] = __builtin_amdgcn_mfma_f32_16x16x32_bf16(af[m], bfr[n], acc[m][n], 0, 0, 0);
    __syncthreads();   // also guarantees staging no longer needed
  }

  // ---- u tile -> LDS, row stride 136 elements (272 B) to spread banks ----
  const int rq = (lane >> 4) * 4;
  const int colf = lane & 15;
  #pragma unroll
  for (int m = 0; m < 4; ++m)
    #pragma unroll
    for (int n = 0; n < 4; ++n)
      #pragma unroll
      for (int i = 0; i < 4; ++i)
        S[(wr * 64 + m * 16 + rq + i) * 136 + (wc * 64 + n * 16 + colf)] =
            f2bf(acc[m][n][i]);
  __syncthreads();

  // ---- score phase: 8 groups of 8 lanes per wave; each group owns one batch row ----
  const int g8 = lane >> 3;
  const int l8 = lane & 7;
  #pragma unroll
  for (int bi = 0; bi < 4; ++bi) {
    const int bl = bi * 32 + wave * 8 + g8;
    const size_t b = bm + bl;

    // u slice for this (batch, lane): 16 bf16 from LDS -> regs (reused for all 17 j)
    float uf[16];
    {
      const unsigned short* up = S + bl * 136 + l8 * 16;
      short8 u0 = *(const short8*)up;
      short8 u1 = *(const short8*)(up + 8);
      #pragma unroll
      for (int t = 0; t < 8; ++t) {
        uf[t]     = bf2f((unsigned short)u0[t]);
        uf[t + 8] = bf2f((unsigned short)u1[t]);
      }
    }

    // j = 0: dot(u, q) over this dim slice
    {
      const unsigned short* qp = qbf + b * DIM + bn + l8 * 16;
      short8 q0 = *(const short8*)qp;
      short8 q1 = *(const short8*)(qp + 8);
      float d = 0.f;
      #pragma unroll
      for (int t = 0; t < 8; ++t)
        d += uf[t] * bf2f((unsigned short)q0[t]) + uf[t + 8] * bf2f((unsigned short)q1[t]);
      d += __shfl_xor(d, 1); d += __shfl_xor(d, 2); d += __shfl_xor(d, 4);
      if (l8 == 0) atomicAdd(&scores[b * SCP], d);
    }

    // j = 1..16: dot(u, k_j) over this dim slice
    const float* kp = key + (b * KV) * DIM + bn + l8 * 16;
    #pragma unroll
    for (int j = 1; j <= KV; ++j) {
      const f32x4* kk = (const f32x4*)(kp + (size_t)(j - 1) * DIM);
      f32x4 k0 = __builtin_nontemporal_load(kk);
      f32x4 k1 = __builtin_nontemporal_load(kk + 1);
      f32x4 k2 = __builtin_nontemporal_load(kk + 2);
      f32x4 k3 = __builtin_nontemporal_load(kk + 3);
      float d = uf[0] * k0.x + uf[1] * k0.y + uf[2] * k0.z + uf[3] * k0.w
              + uf[4] * k1.x + uf[5] * k1.y + uf[6] * k1.z + uf[7] * k1.w
              + uf[8] * k2.x + uf[9] * k2.y + uf[10] * k2.z + uf[11] * k2.w
              + uf[12] * k3.x + uf[13] * k3.y + uf[14] * k3.z + uf[15] * k3.w;
      d += __shfl_xor(d, 1); d += __shfl_xor(d, 2); d += __shfl_xor(d, 4);
      if (l8 == 0) atomicAdd(&scores[b * SCP + j], d);
    }
  }
}

// ---------------- kernel 5: light epilogue (V-stream only) ----------------
// per batch: softmax(scores/32), alpha = sigmoid(q.Wa + ba),
// out = normalize(q*(1 + am*w0) + am * sum_j w_j v_j)
__global__ __launch_bounds__(256) void epilogue(const unsigned short* __restrict__ qbf,
                                                const float* __restrict__ value,
                                                const float* __restrict__ Wa,
                                                const float* __restrict__ ba,
                                                const float* __restrict__ scores,
                                                float* __restrict__ out) {
  const int b = blockIdx.x;
  const int tid = threadIdx.x;
  const int lane = tid & 63, wave = tid >> 6;

  // q slice (4 dims per thread) + Wa slice
  ushort4 q4 = *(const ushort4*)(qbf + (size_t)b * DIM + tid * 4);
  f32x4 qf;
  qf.x = bf2f(q4.x); qf.y = bf2f(q4.y); qf.z = bf2f(q4.z); qf.w = bf2f(q4.w);
  f32x4 w4 = ((const f32x4*)Wa)[tid];

  // prefetch all 16 V slices (hide HBM latency under softmax + reduce)
  const f32x4* v4 = (const f32x4*)(value + (size_t)b * KV * DIM) + tid;
  f32x4 vv[16];
  #pragma unroll
  for (int j = 0; j < 16; ++j)
    vv[j] = __builtin_nontemporal_load(v4 + j * 256);

  // scores (wave-uniform scalar loads, L2-resident)
  const float* srow = scores + (size_t)b * SCP;
  float s[17];
  #pragma unroll
  for (int j = 0; j < 17; ++j) s[j] = srow[j];

  float mx = -1e30f;
  #pragma unroll
  for (int j = 0; j < 17; ++j) { s[j] *= 0.03125f; mx = fmaxf(mx, s[j]); }
  float den = 0.f;
  #pragma unroll
  for (int j = 0; j < 17; ++j) { s[j] = expf(s[j] - mx); den += s[j]; }

  // alpha dot: block reduce
  float ad = dot4(qf, w4);
  #pragma unroll
  for (int m = 32; m >= 1; m >>= 1) ad += __shfl_xor(ad, m);
  __shared__ float rA[4];
  if (lane == 0) rA[wave] = ad;
  __syncthreads();
  float adt = rA[0] + rA[1] + rA[2] + rA[3] + ba[0];
  float alpha = 1.f / (1.f + expf(-adt));
  float am = alpha / den;

  f32x4 t = qf * (1.f + am * s[0]);
  #pragma unroll
  for (int j = 1; j <= 16; ++j) t += vv[j - 1] * (am * s[j]);

  float nq = dot4(t, t);
  #pragma unroll
  for (int m = 32; m >= 1; m >>= 1) nq += __shfl_xor(nq, m);
  __shared__ float rB[4];
  if (lane == 0) rB[wave] = nq;
  __syncthreads();
  float inv = 1.f / fmaxf(sqrtf(rB[0] + rB[1] + rB[2] + rB[3]), 1e-12f);

  ((f32x4*)(out + (size_t)b * DIM))[tid] = t * inv;
}

// ---------------- launcher ----------------
extern "C" void kernel_launch(void* const* d_in, const int* in_sizes, int n_in,
                              void* d_out, int out_size, void* d_ws, size_t ws_size,
                              hipStream_t stream) {
  const float* query = (const float*)d_in[0];
  const float* key   = (const float*)d_in[1];
  const float* value = (const float*)d_in[2];
  const float* Wq    = (const float*)d_in[3];
  const float* Wk    = (const float*)d_in[4];
  const float* Wa    = (const float*)d_in[5];
  const float* ba    = (const float*)d_in[6];

  unsigned short* qbf = (unsigned short*)d_ws;              // 16 MiB
  unsigned short* WqT = qbf + (size_t)BATCH * DIM;          //  2 MiB
  unsigned short* WkT = WqT + (size_t)DIM * DIM;            //  2 MiB
  unsigned short* Mt  = WkT + (size_t)DIM * DIM;            //  2 MiB
  float* scores = (float*)(Mt + (size_t)DIM * DIM);         //  640 KiB [8192][20]

  // q -> bf16; zero the scores accumulator
  convert_q<<<2048, 256, 0, stream>>>((const f32x4*)query, (ushort4*)qbf, BATCH * DIM / 4,
                                      (f32x4*)scores, BATCH * SCP / 4);
  transpose_w<<<dim3(32, 32, 2), dim3(32, 8), 0, stream>>>(Wq, Wk, WqT, WkT);
  // Mt = WkT x WqT^T  (1024^3, bf16 out)
  gemm_nt64<<<dim3(16, 16), 256, 0, stream>>>(WkT, WqT, Mt, DIM, DIM);
  // u-GEMM + K-stream + partial score atomics (u never hits HBM)
  gemm_u_scores<<<512, 256, 0, stream>>>(qbf, Mt, key, scores);
  // light epilogue: softmax/gate/attn(V)/normalize
  epilogue<<<BATCH, 256, 0, stream>>>(qbf, value, Wa, ba, scores, (float*)d_out);
}

// Round 5
// 246.165 us; speedup vs baseline: 1.2862x; 1.2726x over previous
//
#include <hip/hip_runtime.h>
#include <hip/hip_bf16.h>

#define DIM   1024
#define BATCH 8192
#define KV    16

typedef __attribute__((ext_vector_type(4))) float f32x4;
typedef __attribute__((ext_vector_type(8))) short short8;

static __device__ __forceinline__ unsigned short f2bf(float x) {
  return __builtin_bit_cast(unsigned short, __float2bfloat16(x));
}
static __device__ __forceinline__ float bf2f(unsigned short x) {
  return __bfloat162float(__builtin_bit_cast(__hip_bfloat16, x));
}
static __device__ __forceinline__ float dot4(f32x4 a, f32x4 b) {
  return a.x * b.x + a.y * b.y + a.z * b.z + a.w * b.w;
}

static __device__ __forceinline__ void gl_lds16(const unsigned short* g, unsigned short* l) {
  __builtin_amdgcn_global_load_lds(
      (const __attribute__((address_space(1))) void*)g,
      (__attribute__((address_space(3))) void*)l, 16, 0, 0);
}

// ---------------- kernel 1: merged prep (q->bf16 convert + W transposes) ----------------
// grid (32,32,3): z=2 -> convert chunk, z=0/1 -> transpose Wq/Wk tile
__global__ __launch_bounds__(256) void prep(const float* __restrict__ query,
                                            unsigned short* __restrict__ qbf,
                                            const float* __restrict__ Wq,
                                            const float* __restrict__ Wk,
                                            unsigned short* __restrict__ WqT,
                                            unsigned short* __restrict__ WkT) {
  if (blockIdx.z == 2) {
    int bid = blockIdx.y * 32 + blockIdx.x;     // 0..1023
    int i = bid * 256 + threadIdx.x;
    const f32x4* in = (const f32x4*)query;
    ushort4* out = (ushort4*)qbf;
    #pragma unroll
    for (int r = 0; r < 8; ++r) {
      int idx = i + r * 262144;                 // 1024*256 blocksz stride
      f32x4 f = in[idx];
      ushort4 o;
      o.x = f2bf(f.x); o.y = f2bf(f.y); o.z = f2bf(f.z); o.w = f2bf(f.w);
      out[idx] = o;
    }
  } else {
    __shared__ float tile[32][33];
    const float* src = blockIdx.z ? Wk : Wq;
    unsigned short* dst = blockIdx.z ? WkT : WqT;
    int tx = threadIdx.x & 31, ty = threadIdx.x >> 5;
    int x = blockIdx.x * 32 + tx;
    int y0 = blockIdx.y * 32;
    #pragma unroll
    for (int i = ty; i < 32; i += 8)
      tile[i][tx] = src[(size_t)(y0 + i) * DIM + x];
    __syncthreads();
    int x2 = blockIdx.y * 32 + tx;
    int y2 = blockIdx.x * 32;
    #pragma unroll
    for (int i = ty; i < 32; i += 8)
      dst[(size_t)(y2 + i) * DIM + x2] = f2bf(tile[tx][i]);
  }
}

// ---------------- kernel 2: Mt = WkT x WqT^T, 64x64 tiles (256 blocks) ----------------
__global__ __launch_bounds__(256) void gemm_nt64(const unsigned short* __restrict__ A,
                                                 const unsigned short* __restrict__ B,
                                                 unsigned short* __restrict__ C,
                                                 int N, int K) {
  __shared__ __align__(16) unsigned short As[64 * 32];
  __shared__ __align__(16) unsigned short Bs[64 * 32];
  const int tid = threadIdx.x;
  const int lane = tid & 63;
  const int wave = tid >> 6;
  const int wr = wave >> 1, wc = wave & 1;
  const size_t bm = (size_t)blockIdx.x * 64;
  const size_t bn = (size_t)blockIdx.y * 64;

  f32x4 acc[2][2];
  #pragma unroll
  for (int m = 0; m < 2; ++m)
    #pragma unroll
    for (int n = 0; n < 2; ++n)
      acc[m][n] = (f32x4){0.f, 0.f, 0.f, 0.f};

  const int r0 = tid >> 2;
  const int cc = (tid & 3) * 8;
  const int kg = lane >> 4;
  const int rowf = lane & 15;

  for (int kt = 0; kt < K; kt += 32) {
    gl_lds16(A + (bm + r0) * K + kt + cc, As + tid * 8);
    gl_lds16(B + (bn + r0) * K + kt + cc, Bs + tid * 8);
    __syncthreads();
    short8 af[2], bfr[2];
    #pragma unroll
    for (int m = 0; m < 2; ++m)
      af[m] = *(const short8*)(As + ((wr * 32 + m * 16 + rowf) * 32 + kg * 8));
    #pragma unroll
    for (int n = 0; n < 2; ++n)
      bfr[n] = *(const short8*)(Bs + ((wc * 32 + n * 16 + rowf) * 32 + kg * 8));
    #pragma unroll
    for (int m = 0; m < 2; ++m)
      #pragma unroll
      for (int n = 0; n < 2; ++n)
        acc[m][n] = __builtin_amdgcn_mfma_f32_16x16x32_bf16(af[m], bfr[n], acc[m][n], 0, 0, 0);
    __syncthreads();
  }

  const int rq = (lane >> 4) * 4;
  const int colf = lane & 15;
  #pragma unroll
  for (int m = 0; m < 2; ++m)
    #pragma unroll
    for (int n = 0; n < 2; ++n)
      #pragma unroll
      for (int i = 0; i < 4; ++i)
        C[(bm + wr * 32 + m * 16 + rq + i) * N + bn + wc * 32 + n * 16 + colf] =
            f2bf(acc[m][n][i]);
}

// ---------------- kernel 3: u = qbf x Mt^T, 128x128 tiles, BK=64, bf16 strided out ------
__global__ __launch_bounds__(256) void gemm_u(const unsigned short* __restrict__ A,
                                              const unsigned short* __restrict__ B,
                                              unsigned short* __restrict__ C,
                                              int ntN, int ldc) {
  __shared__ __align__(16) unsigned short As[128 * 64];   // 16 KB
  __shared__ __align__(16) unsigned short Bs[128 * 64];   // 16 KB

  const int cpx = gridDim.x >> 3;          // XCD swizzle (512 % 8 == 0)
  const int wg = (blockIdx.x & 7) * cpx + (blockIdx.x >> 3);
  const size_t bm = (size_t)(wg / ntN) * 128;
  const size_t bn = (size_t)(wg % ntN) * 128;

  const int tid = threadIdx.x;
  const int lane = tid & 63;
  const int wave = tid >> 6;
  const int wr = wave >> 1, wc = wave & 1;

  f32x4 acc[4][4];
  #pragma unroll
  for (int m = 0; m < 4; ++m)
    #pragma unroll
    for (int n = 0; n < 4; ++n)
      acc[m][n] = (f32x4){0.f, 0.f, 0.f, 0.f};

  const int kg = lane >> 4;
  const int rowf = lane & 15;

  for (int kt = 0; kt < DIM; kt += 64) {
    // stage 128x64 bf16 tiles: 1024 chunks of 16B each, 4 per thread
    #pragma unroll
    for (int it = 0; it < 4; ++it) {
      int c = it * 256 + tid;
      int r = c >> 3;
      int ko = (c & 7) * 8;
      gl_lds16(A + (bm + r) * DIM + kt + ko, As + c * 8);
      gl_lds16(B + (bn + r) * DIM + kt + ko, Bs + c * 8);
    }
    __syncthreads();
    #pragma unroll
    for (int ks = 0; ks < 2; ++ks) {
      short8 af[4], bfr[4];
      #pragma unroll
      for (int m = 0; m < 4; ++m)
        af[m] = *(const short8*)(As + (wr * 64 + m * 16 + rowf) * 64 + ks * 32 + kg * 8);
      #pragma unroll
      for (int n = 0; n < 4; ++n)
        bfr[n] = *(const short8*)(Bs + (wc * 64 + n * 16 + rowf) * 64 + ks * 32 + kg * 8);
      #pragma unroll
      for (int m = 0; m < 4; ++m)
        #pragma unroll
        for (int n = 0; n < 4; ++n)
          acc[m][n] = __builtin_amdgcn_mfma_f32_16x16x32_bf16(af[m], bfr[n], acc[m][n], 0, 0, 0);
    }
    __syncthreads();
  }

  const int rq = (lane >> 4) * 4;
  const int colf = lane & 15;
  #pragma unroll
  for (int m = 0; m < 4; ++m)
    #pragma unroll
    for (int n = 0; n < 4; ++n)
      #pragma unroll
      for (int i = 0; i < 4; ++i) {
        size_t row = bm + wr * 64 + m * 16 + rq + i;
        size_t col = bn + wc * 64 + n * 16 + colf;
        C[row * (size_t)ldc + col] = f2bf(acc[m][n][i]);
      }
}

// ---------------- kernel 4: fused attention epilogue (high occupancy, 8192 blocks) ------
// u bf16 strided in d_out (row b at element b*2048); q from qbf (bf16).
__global__ __launch_bounds__(256) void epilogue(const unsigned short* __restrict__ qbf,
                                                const float* __restrict__ key,
                                                const float* __restrict__ value,
                                                const float* __restrict__ Wa,
                                                const float* __restrict__ ba,
                                                const unsigned short* __restrict__ u,
                                                float* __restrict__ out) {
  const int b = blockIdx.x;
  const int tid = threadIdx.x;
  const int lane = tid & 63, wave = tid >> 6;
  const f32x4* k4 = (const f32x4*)(key + (size_t)b * KV * DIM);
  const f32x4* v4 = (const f32x4*)(value + (size_t)b * KV * DIM);

  ushort4 qb4 = *(const ushort4*)(qbf + (size_t)b * DIM + tid * 4);
  f32x4 qv;
  qv.x = bf2f(qb4.x); qv.y = bf2f(qb4.y); qv.z = bf2f(qb4.z); qv.w = bf2f(qb4.w);
  ushort4 ub = ((const ushort4*)(u + (size_t)b * 2048))[tid];
  f32x4 uv;
  uv.x = bf2f(ub.x); uv.y = bf2f(ub.y); uv.z = bf2f(ub.z); uv.w = bf2f(ub.w);
  f32x4 wv = ((const f32x4*)Wa)[tid];

  float s[17];
  s[0] = dot4(qv, uv);
  float ad = dot4(qv, wv);
  #pragma unroll
  for (int j = 1; j <= 16; ++j) {
    f32x4 kv = __builtin_nontemporal_load(k4 + (j - 1) * 256 + tid);
    s[j] = dot4(uv, kv);
  }

  // prefetch all V rows BEFORE the reduction chains
  f32x4 vv[16];
  #pragma unroll
  for (int j = 0; j < 16; ++j)
    vv[j] = __builtin_nontemporal_load(v4 + j * 256 + tid);

  #pragma unroll
  for (int m = 32; m >= 1; m >>= 1) {
    #pragma unroll
    for (int j = 0; j < 17; ++j) s[j] += __shfl_xor(s[j], m);
    ad += __shfl_xor(ad, m);
  }
  __shared__ float red[4][18];
  if (lane == 0) {
    #pragma unroll
    for (int j = 0; j < 17; ++j) red[wave][j] = s[j];
    red[wave][17] = ad;
  }
  __syncthreads();

  float wt[17];
  float mx = -1e30f;
  #pragma unroll
  for (int j = 0; j < 17; ++j) {
    float t = (red[0][j] + red[1][j] + red[2][j] + red[3][j]) * 0.03125f;
    wt[j] = t;
    mx = fmaxf(mx, t);
  }
  float den = 0.f;
  #pragma unroll
  for (int j = 0; j < 17; ++j) {
    wt[j] = expf(wt[j] - mx);
    den += wt[j];
  }
  float adt = red[0][17] + red[1][17] + red[2][17] + red[3][17] + ba[0];
  float alpha = 1.0f / (1.0f + expf(-adt));
  float am = alpha / den;

  f32x4 acc = qv * wt[0];
  #pragma unroll
  for (int j = 1; j <= 16; ++j) acc += vv[j - 1] * wt[j];
  f32x4 t = qv + acc * am;

  float ssp = dot4(t, t);
  #pragma unroll
  for (int m = 32; m >= 1; m >>= 1) ssp += __shfl_xor(ssp, m);
  __shared__ float red2[4];
  if (lane == 0) red2[wave] = ssp;
  __syncthreads();
  float nrm = sqrtf(red2[0] + red2[1] + red2[2] + red2[3]);
  float inv = 1.0f / fmaxf(nrm, 1e-12f);

  __builtin_nontemporal_store(t * inv, (f32x4*)(out + (size_t)b * DIM) + tid);
}

// ---------------- launcher ----------------
extern "C" void kernel_launch(void* const* d_in, const int* in_sizes, int n_in,
                              void* d_out, int out_size, void* d_ws, size_t ws_size,
                              hipStream_t stream) {
  const float* query = (const float*)d_in[0];
  const float* key   = (const float*)d_in[1];
  const float* value = (const float*)d_in[2];
  const float* Wq    = (const float*)d_in[3];
  const float* Wk    = (const float*)d_in[4];
  const float* Wa    = (const float*)d_in[5];
  const float* ba    = (const float*)d_in[6];

  unsigned short* qbf = (unsigned short*)d_ws;              // 16 MiB
  unsigned short* WqT = qbf + (size_t)BATCH * DIM;          //  2 MiB
  unsigned short* WkT = WqT + (size_t)DIM * DIM;            //  2 MiB
  unsigned short* Mt  = WkT + (size_t)DIM * DIM;            //  2 MiB
  unsigned short* ubf = (unsigned short*)d_out;             // strided bf16 u inside d_out

  // q -> bf16 + W transposes (one kernel)
  prep<<<dim3(32, 32, 3), 256, 0, stream>>>(query, qbf, Wq, Wk, WqT, WkT);
  // Mt = WkT x WqT^T  (1024^3, bf16 out)
  gemm_nt64<<<dim3(16, 16), 256, 0, stream>>>(WkT, WqT, Mt, DIM, DIM);
  // u = qbf x Mt^T, BK=64, bf16 out strided ldc=2048 into d_out
  gemm_u<<<512, 256, 0, stream>>>(qbf, Mt, ubf, DIM / 128, 2048);
  // fused scores/softmax/attn/gate/normalize
  epilogue<<<BATCH, 256, 0, stream>>>(qbf, key, value, Wa, ba, ubf, (float*)d_out);
}

// Round 6
// 244.324 us; speedup vs baseline: 1.2959x; 1.0075x over previous
//
#include <hip/hip_runtime.h>
#include <hip/hip_bf16.h>

#define DIM   1024
#define BATCH 8192
#define KV    16

typedef __attribute__((ext_vector_type(4))) float f32x4;
typedef __attribute__((ext_vector_type(8))) short short8;

static __device__ __forceinline__ unsigned short f2bf(float x) {
  return __builtin_bit_cast(unsigned short, __float2bfloat16(x));
}
static __device__ __forceinline__ float bf2f(unsigned short x) {
  return __bfloat162float(__builtin_bit_cast(__hip_bfloat16, x));
}
static __device__ __forceinline__ float dot4(f32x4 a, f32x4 b) {
  return a.x * b.x + a.y * b.y + a.z * b.z + a.w * b.w;
}

static __device__ __forceinline__ void gl_lds16(const unsigned short* g, unsigned short* l) {
  __builtin_amdgcn_global_load_lds(
      (const __attribute__((address_space(1))) void*)g,
      (__attribute__((address_space(3))) void*)l, 16, 0, 0);
}

// ---------------- kernel 1: Wq,Wk f32 -> transposed bf16 ----------------
__global__ __launch_bounds__(256) void transpose_w(const float* __restrict__ Wq,
                                                   const float* __restrict__ Wk,
                                                   unsigned short* __restrict__ WqT,
                                                   unsigned short* __restrict__ WkT) {
  __shared__ float tile[32][33];
  const float* src = blockIdx.z ? Wk : Wq;
  unsigned short* dst = blockIdx.z ? WkT : WqT;
  int tx = threadIdx.x & 31, ty = threadIdx.x >> 5;
  int x = blockIdx.x * 32 + tx;
  int y0 = blockIdx.y * 32;
  #pragma unroll
  for (int i = ty; i < 32; i += 8)
    tile[i][tx] = src[(size_t)(y0 + i) * DIM + x];
  __syncthreads();
  int x2 = blockIdx.y * 32 + tx;
  int y2 = blockIdx.x * 32;
  #pragma unroll
  for (int i = ty; i < 32; i += 8)
    dst[(size_t)(y2 + i) * DIM + x2] = f2bf(tile[tx][i]);
}

// ---------------- kernel 2: Mt = WkT x WqT^T, 64x64 tiles (256 blocks) ----------------
__global__ __launch_bounds__(256) void gemm_nt64(const unsigned short* __restrict__ A,
                                                 const unsigned short* __restrict__ B,
                                                 unsigned short* __restrict__ C,
                                                 int N, int K) {
  __shared__ __align__(16) unsigned short As[64 * 32];
  __shared__ __align__(16) unsigned short Bs[64 * 32];
  const int tid = threadIdx.x;
  const int lane = tid & 63;
  const int wave = tid >> 6;
  const int wr = wave >> 1, wc = wave & 1;
  const size_t bm = (size_t)blockIdx.x * 64;
  const size_t bn = (size_t)blockIdx.y * 64;

  f32x4 acc[2][2];
  #pragma unroll
  for (int m = 0; m < 2; ++m)
    #pragma unroll
    for (int n = 0; n < 2; ++n)
      acc[m][n] = (f32x4){0.f, 0.f, 0.f, 0.f};

  const int r0 = tid >> 2;
  const int cc = (tid & 3) * 8;
  const int kg = lane >> 4;
  const int rowf = lane & 15;

  for (int kt = 0; kt < K; kt += 32) {
    gl_lds16(A + (bm + r0) * K + kt + cc, As + tid * 8);
    gl_lds16(B + (bn + r0) * K + kt + cc, Bs + tid * 8);
    __syncthreads();
    short8 af[2], bfr[2];
    #pragma unroll
    for (int m = 0; m < 2; ++m)
      af[m] = *(const short8*)(As + ((wr * 32 + m * 16 + rowf) * 32 + kg * 8));
    #pragma unroll
    for (int n = 0; n < 2; ++n)
      bfr[n] = *(const short8*)(Bs + ((wc * 32 + n * 16 + rowf) * 32 + kg * 8));
    #pragma unroll
    for (int m = 0; m < 2; ++m)
      #pragma unroll
      for (int n = 0; n < 2; ++n)
        acc[m][n] = __builtin_amdgcn_mfma_f32_16x16x32_bf16(af[m], bfr[n], acc[m][n], 0, 0, 0);
    __syncthreads();
  }

  const int rq = (lane >> 4) * 4;
  const int colf = lane & 15;
  #pragma unroll
  for (int m = 0; m < 2; ++m)
    #pragma unroll
    for (int n = 0; n < 2; ++n)
      #pragma unroll
      for (int i = 0; i < 4; ++i)
        C[(bm + wr * 32 + m * 16 + rq + i) * N + bn + wc * 32 + n * 16 + colf] =
            f2bf(acc[m][n][i]);
}

// ---------------- kernel 3: u = query(f32) x Mt^T, 128x128, BK=32 ----------------
// A staged reg-side with inline f32->bf16 conversion (coalesced f32x4 loads,
// ds_write 8B); B staged via global_load_lds. bf16 out, strided into d_out.
__global__ __launch_bounds__(256) void gemm_u(const float* __restrict__ Af,
                                              const unsigned short* __restrict__ B,
                                              unsigned short* __restrict__ C,
                                              int ntN, int ldc) {
  __shared__ __align__(16) unsigned short As[128 * 32];   // 8 KB
  __shared__ __align__(16) unsigned short Bs[128 * 32];   // 8 KB

  const int cpx = gridDim.x >> 3;          // XCD swizzle (512 % 8 == 0)
  const int wg = (blockIdx.x & 7) * cpx + (blockIdx.x >> 3);
  const size_t bm = (size_t)(wg / ntN) * 128;
  const size_t bn = (size_t)(wg % ntN) * 128;

  const int tid = threadIdx.x;
  const int lane = tid & 63;
  const int wave = tid >> 6;
  const int wr = wave >> 1, wc = wave & 1;

  f32x4 acc[4][4];
  #pragma unroll
  for (int m = 0; m < 4; ++m)
    #pragma unroll
    for (int n = 0; n < 4; ++n)
      acc[m][n] = (f32x4){0.f, 0.f, 0.f, 0.f};

  const int kg = lane >> 4;
  const int rowf = lane & 15;
  const int br0 = tid >> 2;                // B chunk row (chunks of 8 bf16)
  const int bcc = (tid & 3) * 8;

  for (int kt = 0; kt < DIM; kt += 32) {
    // B: 128x32 bf16 = 8 KB, 512 x 16B chunks, 2 per thread (global_load_lds)
    gl_lds16(B + (bn + br0) * DIM + kt + bcc, Bs + tid * 8);
    gl_lds16(B + (bn + 64 + br0) * DIM + kt + bcc, Bs + 2048 + tid * 8);
    // A: 128x32 f32 = 16 KB, 1024 x 16B chunks, 4 per thread; cvt -> bf16 ds_write
    #pragma unroll
    for (int it = 0; it < 4; ++it) {
      int c = it * 256 + tid;
      int r = c >> 3;                      // 8 chunks per 32-f32 row
      int ko = (c & 7) * 4;
      f32x4 f = *(const f32x4*)(Af + (bm + r) * DIM + kt + ko);
      ushort4 o;
      o.x = f2bf(f.x); o.y = f2bf(f.y); o.z = f2bf(f.z); o.w = f2bf(f.w);
      *(ushort4*)(As + r * 32 + ko) = o;
    }
    __syncthreads();
    short8 af[4], bfr[4];
    #pragma unroll
    for (int m = 0; m < 4; ++m)
      af[m] = *(const short8*)(As + ((wr * 64 + m * 16 + rowf) * 32 + kg * 8));
    #pragma unroll
    for (int n = 0; n < 4; ++n)
      bfr[n] = *(const short8*)(Bs + ((wc * 64 + n * 16 + rowf) * 32 + kg * 8));
    #pragma unroll
    for (int m = 0; m < 4; ++m)
      #pragma unroll
      for (int n = 0; n < 4; ++n)
        acc[m][n] = __builtin_amdgcn_mfma_f32_16x16x32_bf16(af[m], bfr[n], acc[m][n], 0, 0, 0);
    __syncthreads();
  }

  const int rq = (lane >> 4) * 4;
  const int colf = lane & 15;
  #pragma unroll
  for (int m = 0; m < 4; ++m)
    #pragma unroll
    for (int n = 0; n < 4; ++n)
      #pragma unroll
      for (int i = 0; i < 4; ++i) {
        size_t row = bm + wr * 64 + m * 16 + rq + i;
        size_t col = bn + wc * 64 + n * 16 + colf;
        C[row * (size_t)ldc + col] = f2bf(acc[m][n][i]);
      }
}

// ---------------- kernel 4: fused attention epilogue (8192 blocks) ----------------
// u bf16 strided in d_out (row b at element b*2048); q read as f32 (exact residual).
__global__ __launch_bounds__(256) void epilogue(const float* __restrict__ query,
                                                const float* __restrict__ key,
                                                const float* __restrict__ value,
                                                const float* __restrict__ Wa,
                                                const float* __restrict__ ba,
                                                const unsigned short* __restrict__ u,
                                                float* __restrict__ out) {
  const int b = blockIdx.x;
  const int tid = threadIdx.x;
  const int lane = tid & 63, wave = tid >> 6;
  const f32x4* k4 = (const f32x4*)(key + (size_t)b * KV * DIM);
  const f32x4* v4 = (const f32x4*)(value + (size_t)b * KV * DIM);

  f32x4 qv = ((const f32x4*)(query + (size_t)b * DIM))[tid];
  ushort4 ub = ((const ushort4*)(u + (size_t)b * 2048))[tid];
  f32x4 uv;
  uv.x = bf2f(ub.x); uv.y = bf2f(ub.y); uv.z = bf2f(ub.z); uv.w = bf2f(ub.w);
  f32x4 wv = ((const f32x4*)Wa)[tid];

  float s[17];
  s[0] = dot4(qv, uv);
  float ad = dot4(qv, wv);
  #pragma unroll
  for (int j = 1; j <= 16; ++j) {
    f32x4 kv = __builtin_nontemporal_load(k4 + (j - 1) * 256 + tid);
    s[j] = dot4(uv, kv);
  }

  // prefetch all V rows BEFORE the reduction chains
  f32x4 vv[16];
  #pragma unroll
  for (int j = 0; j < 16; ++j)
    vv[j] = __builtin_nontemporal_load(v4 + j * 256 + tid);

  #pragma unroll
  for (int m = 32; m >= 1; m >>= 1) {
    #pragma unroll
    for (int j = 0; j < 17; ++j) s[j] += __shfl_xor(s[j], m);
    ad += __shfl_xor(ad, m);
  }
  __shared__ float red[4][18];
  if (lane == 0) {
    #pragma unroll
    for (int j = 0; j < 17; ++j) red[wave][j] = s[j];
    red[wave][17] = ad;
  }
  __syncthreads();

  float wt[17];
  float mx = -1e30f;
  #pragma unroll
  for (int j = 0; j < 17; ++j) {
    float t = (red[0][j] + red[1][j] + red[2][j] + red[3][j]) * 0.03125f;
    wt[j] = t;
    mx = fmaxf(mx, t);
  }
  float den = 0.f;
  #pragma unroll
  for (int j = 0; j < 17; ++j) {
    wt[j] = expf(wt[j] - mx);
    den += wt[j];
  }
  float adt = red[0][17] + red[1][17] + red[2][17] + red[3][17] + ba[0];
  float alpha = 1.0f / (1.0f + expf(-adt));
  float am = alpha / den;

  f32x4 acc = qv * wt[0];
  #pragma unroll
  for (int j = 1; j <= 16; ++j) acc += vv[j - 1] * wt[j];
  f32x4 t = qv + acc * am;

  float ssp = dot4(t, t);
  #pragma unroll
  for (int m = 32; m >= 1; m >>= 1) ssp += __shfl_xor(ssp, m);
  __shared__ float red2[4];
  if (lane == 0) red2[wave] = ssp;
  __syncthreads();
  float nrm = sqrtf(red2[0] + red2[1] + red2[2] + red2[3]);
  float inv = 1.0f / fmaxf(nrm, 1e-12f);

  __builtin_nontemporal_store(t * inv, (f32x4*)(out + (size_t)b * DIM) + tid);
}

// ---------------- launcher ----------------
extern "C" void kernel_launch(void* const* d_in, const int* in_sizes, int n_in,
                              void* d_out, int out_size, void* d_ws, size_t ws_size,
                              hipStream_t stream) {
  const float* query = (const float*)d_in[0];
  const float* key   = (const float*)d_in[1];
  const float* value = (const float*)d_in[2];
  const float* Wq    = (const float*)d_in[3];
  const float* Wk    = (const float*)d_in[4];
  const float* Wa    = (const float*)d_in[5];
  const float* ba    = (const float*)d_in[6];

  unsigned short* WqT = (unsigned short*)d_ws;              // 2 MiB
  unsigned short* WkT = WqT + (size_t)DIM * DIM;            // 2 MiB
  unsigned short* Mt  = WkT + (size_t)DIM * DIM;            // 2 MiB
  unsigned short* ubf = (unsigned short*)d_out;             // strided bf16 u inside d_out

  // W transposes (bf16)
  transpose_w<<<dim3(32, 32, 2), 256, 0, stream>>>(Wq, Wk, WqT, WkT);
  // Mt = WkT x WqT^T  (1024^3, bf16 out)
  gemm_nt64<<<dim3(16, 16), 256, 0, stream>>>(WkT, WqT, Mt, DIM, DIM);
  // u = query(f32) x Mt^T, BK=32, inline conversion; bf16 out strided ldc=2048
  gemm_u<<<512, 256, 0, stream>>>(query, Mt, ubf, DIM / 128, 2048);
  // fused scores/softmax/attn/gate/normalize (f32 q)
  epilogue<<<BATCH, 256, 0, stream>>>(query, key, value, Wa, ba, ubf, (float*)d_out);
}